// Round 1
// baseline (48.444 us; speedup 1.0000x reference)
//
#include <hip/hip_runtime.h>

// SVMProjection: out[n,d] = x[n,d] - (dot(x[n,:],cav) - dot(bias,cav)) * cav[d]
// N=8192 rows, D=4096 cols, fp32 in/out. Memory-bound: read x once + write out.

#define DIM 4096
#define NTHREADS 256
#define V4_PER_ROW (DIM / 4)          // 1024 float4 per row
#define V4_PER_THREAD (V4_PER_ROW / NTHREADS)  // 4

// Kernel 1: bproj = dot(bias, cav) -> ws[0]
__global__ void __launch_bounds__(NTHREADS)
svm_bproj_kernel(const float* __restrict__ bias, const float* __restrict__ cav,
                 float* __restrict__ ws) {
    int t = threadIdx.x;
    const float4* b4 = reinterpret_cast<const float4*>(bias);
    const float4* c4 = reinterpret_cast<const float4*>(cav);
    float s = 0.0f;
    #pragma unroll
    for (int k = 0; k < V4_PER_THREAD; ++k) {
        int i = t + k * NTHREADS;
        float4 b = b4[i];
        float4 c = c4[i];
        s += b.x * c.x + b.y * c.y + b.z * c.z + b.w * c.w;
    }
    // wave64 reduce
    #pragma unroll
    for (int off = 32; off > 0; off >>= 1) s += __shfl_down(s, off, 64);
    __shared__ float ls[NTHREADS / 64];
    int wave = t >> 6;
    if ((t & 63) == 0) ls[wave] = s;
    __syncthreads();
    if (t == 0) {
        float tot = 0.0f;
        #pragma unroll
        for (int w = 0; w < NTHREADS / 64; ++w) tot += ls[w];
        ws[0] = tot;
    }
}

// Kernel 2: one block per row. Row held in registers; dot -> block reduce -> write.
__global__ void __launch_bounds__(NTHREADS)
svm_proj_kernel(const float* __restrict__ x, const float* __restrict__ cav,
                const float* __restrict__ ws, float* __restrict__ out) {
    const int row = blockIdx.x;
    const int t = threadIdx.x;

    const float4* xr = reinterpret_cast<const float4*>(x + (size_t)row * DIM);
    const float4* c4 = reinterpret_cast<const float4*>(cav);

    float4 xv[V4_PER_THREAD];
    float4 cv[V4_PER_THREAD];
    float s = 0.0f;
    #pragma unroll
    for (int k = 0; k < V4_PER_THREAD; ++k) {
        int i = t + k * NTHREADS;        // coalesced: lane-contiguous float4
        xv[k] = xr[i];
        cv[k] = c4[i];
        s += xv[k].x * cv[k].x + xv[k].y * cv[k].y
           + xv[k].z * cv[k].z + xv[k].w * cv[k].w;
    }

    // wave64 butterfly-ish reduce (shfl_down), then cross-wave via LDS
    #pragma unroll
    for (int off = 32; off > 0; off >>= 1) s += __shfl_down(s, off, 64);

    __shared__ float ls[NTHREADS / 64];
    int wave = t >> 6;
    if ((t & 63) == 0) ls[wave] = s;
    __syncthreads();

    float proj = 0.0f;
    #pragma unroll
    for (int w = 0; w < NTHREADS / 64; ++w) proj += ls[w];

    const float sc = proj - ws[0];   // (x·cav - bias·cav)

    float4* orow = reinterpret_cast<float4*>(out + (size_t)row * DIM);
    #pragma unroll
    for (int k = 0; k < V4_PER_THREAD; ++k) {
        int i = t + k * NTHREADS;
        float4 o;
        o.x = xv[k].x - sc * cv[k].x;
        o.y = xv[k].y - sc * cv[k].y;
        o.z = xv[k].z - sc * cv[k].z;
        o.w = xv[k].w - sc * cv[k].w;
        orow[i] = o;
    }
}

extern "C" void kernel_launch(void* const* d_in, const int* in_sizes, int n_in,
                              void* d_out, int out_size, void* d_ws, size_t ws_size,
                              hipStream_t stream) {
    const float* x    = reinterpret_cast<const float*>(d_in[0]);
    const float* cav  = reinterpret_cast<const float*>(d_in[1]);
    const float* bias = reinterpret_cast<const float*>(d_in[2]);
    float* out = reinterpret_cast<float*>(d_out);
    float* ws  = reinterpret_cast<float*>(d_ws);

    const int N = in_sizes[0] / DIM;   // 8192

    svm_bproj_kernel<<<1, NTHREADS, 0, stream>>>(bias, cav, ws);
    svm_proj_kernel<<<N, NTHREADS, 0, stream>>>(x, cav, ws, out);
}